// Round 5
// baseline (43.371 us; speedup 1.0000x reference)
//
#include <hip/hip_runtime.h>
#include <math.h>

#define NT 365
#define NT2 368
#define NS 128
#define NG 16
#define NH 8
#define HS 256
#define NSNH (NS * NH)
#define EPSC 1e-6f

// Workspace layout (floats):
//   prm: 6*NS*NH @ 0      order: gk, gl, qb, ga, gi, ge
//   P:   16*NT2*64*4 @ 8192   packed float4 {km, ps, pl, ev} per (blk,t,lane)
#define WS_PRM 0
#define WS_P   8192

__device__ __forceinline__ float fast_rcp(float v) {
#if __has_builtin(__builtin_amdgcn_rcpf)
    return __builtin_amdgcn_rcpf(v);
#else
    return 1.f / v;
#endif
}
__device__ __forceinline__ float fexp2(float v) {
#if __has_builtin(__builtin_amdgcn_exp2f)
    return __builtin_amdgcn_exp2f(v);
#else
    return exp2f(v);
#endif
}
// tanh(x) = 1 - 2/(exp(2x)+1); exp(2x) = exp2(x * 2*log2(e))
#define TWO_LOG2E 2.8853900817779268f

// ---------------- K_main: forcing, one THREAD per (t,s) ------------------
// 256 blocks x 256. Block = (site s = blockIdx&127, t-half th = blockIdx>>7).
// Threads 0..183 each own t = th*184 + tid. All lanes of a wave share s, so
// the j-loop's LDS reads (u0, W_kin, W_koutT) are same-address broadcasts.
// Blocks 0..127 additionally compute prm[site].
__global__ __launch_bounds__(256) void k_main(
    const float* __restrict__ x, const float* __restrict__ xc,
    const float* __restrict__ W_fc, const float* __restrict__ b_fc,
    const float* __restrict__ W_g, const float* __restrict__ b_g,
    const float* __restrict__ W_kin, const float* __restrict__ b_kin,
    const float* __restrict__ W_kout, const float* __restrict__ b_kout,
    float* __restrict__ prm, float4* __restrict__ P)
{
    __shared__ float u0[HS];                 // state + b_kin
    __shared__ float ts[HS];                 // tanh(state)
    __shared__ __align__(16) float4 wkin_lds[HS];
    __shared__ __align__(16) float4 wkoA[HS];   // W_kout[0..3][j]
    __shared__ __align__(16) float4 wkoB[HS];   // W_kout[4..7][j]
    __shared__ float pgs[6 * NH];

    int tid = threadIdx.x;
    int s = blockIdx.x & 127;
    int th = blockIdx.x >> 7;                // 0 or 1

    // stage W_kin and transposed W_kout (coalesced reads, one pass per block)
    wkin_lds[tid] = ((const float4*)W_kin)[tid];
    {
        float4 va, vb;
        va.x = W_kout[0 * HS + tid]; va.y = W_kout[1 * HS + tid];
        va.z = W_kout[2 * HS + tid]; va.w = W_kout[3 * HS + tid];
        vb.x = W_kout[4 * HS + tid]; vb.y = W_kout[5 * HS + tid];
        vb.z = W_kout[6 * HS + tid]; vb.w = W_kout[7 * HS + tid];
        wkoA[tid] = va; wkoB[tid] = vb;
    }
    // state row tid for this block's site
    {
        float a = b_fc[tid];
        const float4* wf = (const float4*)(W_fc + tid * NG);
        const float* xr = xc + s * NG;
#pragma unroll
        for (int i = 0; i < 4; ++i) {
            float4 w = wf[i];
            a += xr[4*i] * w.x + xr[4*i+1] * w.y + xr[4*i+2] * w.z + xr[4*i+3] * w.w;
        }
        ts[tid] = tanhf(a);
        u0[tid] = a + b_kin[tid];
    }
    __syncthreads();

    // fused param heads for blocks 0..127 (site == blockIdx)
    if (blockIdx.x < NS) {
        int wave = tid >> 6, lane = tid & 63;
        for (int k = wave; k < 6 * NH; k += 4) {
            float p = 0.f;
#pragma unroll
            for (int r = 0; r < 4; ++r) {
                int jj = lane + 64 * r;
                p += ts[jj] * W_g[k * HS + jj];
            }
#pragma unroll
            for (int off = 32; off; off >>= 1) p += __shfl_xor(p, off, 64);
            if (lane == 0) pgs[k] = p + b_g[k];
        }
        __syncthreads();
        if (tid < NH) {
            int hh = tid;
            float gk = expf(pgs[hh]) * 0.01f;
            float gl = expf(pgs[NH + hh]) * 100.f;
            float qb = fmaxf(pgs[2 * NH + hh], 0.f) * 0.1f;
            float m = pgs[3 * NH];
#pragma unroll
            for (int i = 1; i < NH; ++i) m = fmaxf(m, pgs[3 * NH + i]);
            float den = 0.f;
#pragma unroll
            for (int i = 0; i < NH; ++i) den += expf(pgs[3 * NH + i] - m);
            float ga = expf(pgs[3 * NH + hh] - m) / den;
            float gi = fminf(fmaxf(pgs[4 * NH + hh] * (1.f / 6.f) + 0.5f, 0.f), 1.f) * 0.5f;
            float ge = fmaxf(pgs[5 * NH + hh], 0.f);
            int o = s * NH + hh;
            prm[0 * NSNH + o] = gk;
            prm[1 * NSNH + o] = gl;
            prm[2 * NSNH + o] = qb;
            prm[3 * NSNH + o] = ga;
            prm[4 * NSNH + o] = gi;
            prm[5 * NSNH + o] = ge;
        }
    }

    if (tid >= 184) return;                  // forcing role: threads 0..183
    int t = th * 184 + tid;                  // 0..367
    float4* Pb = P + ((size_t)(s >> 3) * NT2 + t) * 64 + (s & 7) * 8;

    if (t >= NT) {                           // zero-pad t = 365..367
        float4 z = make_float4(0.f, 0.f, 0.f, 0.f);
#pragma unroll
        for (int h = 0; h < NH; ++h) Pb[h] = z;
        return;
    }

    const float* xr = x + (size_t)(t * NS + s) * 6;
    float prcp = xr[0], ev = xr[1], f0 = xr[2], f1 = xr[3], f2 = xr[4], f3 = xr[5];

    float a0 = 0.f, a1 = 0.f, a2 = 0.f, a3 = 0.f;
    float a4 = 0.f, a5 = 0.f, a6 = 0.f, a7 = 0.f;
#pragma unroll 4
    for (int j = 0; j < HS; ++j) {
        float4 w = wkin_lds[j];
        float arg = u0[j];
        arg = fmaf(f0, w.x, arg);
        arg = fmaf(f1, w.y, arg);
        arg = fmaf(f2, w.z, arg);
        arg = fmaf(f3, w.w, arg);
        float e = fexp2(arg * TWO_LOG2E);
        float tn = 1.f - 2.f * fast_rcp(e + 1.f);   // overflow->inf->0->1 ok
        float4 wa = wkoA[j], wb = wkoB[j];
        a0 = fmaf(tn, wa.x, a0); a1 = fmaf(tn, wa.y, a1);
        a2 = fmaf(tn, wa.z, a2); a3 = fmaf(tn, wa.w, a3);
        a4 = fmaf(tn, wb.x, a4); a5 = fmaf(tn, wb.y, a5);
        a6 = fmaf(tn, wb.z, a6); a7 = fmaf(tn, wb.w, a7);
    }

    // rain/snow split
    float r_ = (f0 + f1) / fmaxf(f1 - f0, EPSC);
    r_ = fminf(fmaxf(r_, -1.f), 1.f);
    float vf = acosf(r_) * 0.31830988618379067f;    // 1/pi
    if (f0 >= 0.f) vf = 0.f;
    if (f1 <= 0.f) vf = 1.f;
    float psv = prcp * vf;
    float plv = prcp * (1.f - vf);

    Pb[0] = make_float4(__expf(a0 + b_kout[0]), psv, plv, ev);
    Pb[1] = make_float4(__expf(a1 + b_kout[1]), psv, plv, ev);
    Pb[2] = make_float4(__expf(a2 + b_kout[2]), psv, plv, ev);
    Pb[3] = make_float4(__expf(a3 + b_kout[3]), psv, plv, ev);
    Pb[4] = make_float4(__expf(a4 + b_kout[4]), psv, plv, ev);
    Pb[5] = make_float4(__expf(a5 + b_kout[5]), psv, plv, ev);
    Pb[6] = make_float4(__expf(a6 + b_kout[6]), psv, plv, ev);
    Pb[7] = make_float4(__expf(a7 + b_kout[7]), psv, plv, ev);
}

// ---------------- K_scan: collapsed scan, 12-slot step, 3-deep pipeline ---
// (byte-identical to R4 — known-good; isolates the k_main delta)
__global__ __launch_bounds__(64, 1) void k_scan(
    const float4* __restrict__ P, const float* __restrict__ prm,
    float* __restrict__ q)
{
    int lane = threadIdx.x;
    int blk = blockIdx.x;               // 0..15
    int sbase = blk * 8;
    int gofs = blk * 64 + lane;         // s*NH + h

    float gk = prm[0 * NSNH + gofs];
    float gl = prm[1 * NSNH + gofs];
    float qb = prm[2 * NSNH + gofs];
    float gi = prm[4 * NSNH + gofs];
    float ge = prm[5 * NSNH + gofs];
    float c1 = 1.f - gk, nqb = -qb, nge = -ge;
    int ss0 = lane & 7;
    float gar[8];                        // ga[site ss0][h] for the REDC role
#pragma unroll
    for (int hh = 0; hh < 8; ++hh)
        gar[hh] = prm[3 * NSNH + (sbase + ss0) * 8 + hh];

    __shared__ float out_lds[64 * 17];
    float S = 0.f, sf = 0.f;
    const float4* Pb = P + (size_t)blk * (NT2 * 64) + lane;

    float4 A[16], B[16], C[16];

#define LOADC(ci, BUF) { const float4* p_ = Pb + (ci) * 1024; _Pragma("unroll") \
    for (int c = 0; c < 16; ++c) BUF[c] = p_[c * 64]; }

#define WORKC(BUF, tb) { \
    _Pragma("unroll") for (int c = 0; c < 16; ++c) { \
        float4 a = BUF[c]; \
        float sf1 = sf + a.y; \
        float melt = fminf(sf1, a.x); \
        sf = sf1 - melt; \
        float Sw = S + fmaf(a.z, gi, melt); \
        float t2v = fmaf(a.w, nge, Sw); \
        float S1 = fmaxf(t2v, 0.f); \
        float S2 = __builtin_amdgcn_fmed3f(t2v, 0.f, gl); \
        float Sn = fmaxf(fmaf(S2, c1, nqb), 0.f); \
        S = Sn; \
        out_lds[lane * 17 + c] = S1 - Sn; \
    } \
    _Pragma("unroll") for (int it = 0; it < 2; ++it) { \
        int idx = it * 64 + lane; int c = idx >> 3; \
        float sum = 0.f; \
        _Pragma("unroll") for (int hh = 0; hh < 8; ++hh) \
            sum = fmaf(gar[hh], out_lds[(ss0 * 8 + hh) * 17 + c], sum); \
        int t = (tb) + c; \
        if (t < NT) q[t * NS + sbase + ss0] = sum; \
    } }

    LOADC(0, A); LOADC(1, B);
    for (int k = 0; k < 7; ++k) {
        int c3 = 3 * k;
        LOADC(c3 + 2, C); WORKC(A, c3 * 16);
        LOADC(c3 + 3, A); WORKC(B, (c3 + 1) * 16);
        LOADC(c3 + 4, B); WORKC(C, (c3 + 2) * 16);
    }
    WORKC(A, 21 * 16); WORKC(B, 22 * 16);
#undef LOADC
#undef WORKC
}

extern "C" void kernel_launch(void* const* d_in, const int* in_sizes, int n_in,
                              void* d_out, int out_size, void* d_ws, size_t ws_size,
                              hipStream_t stream)
{
    const float* x      = (const float*)d_in[0];
    const float* xc     = (const float*)d_in[1];
    const float* W_fc   = (const float*)d_in[2];
    const float* b_fc   = (const float*)d_in[3];
    const float* W_g    = (const float*)d_in[4];
    const float* b_g    = (const float*)d_in[5];
    const float* W_kin  = (const float*)d_in[6];
    const float* b_kin  = (const float*)d_in[7];
    const float* W_kout = (const float*)d_in[8];
    const float* b_kout = (const float*)d_in[9];
    float* q = (float*)d_out;

    float* ws  = (float*)d_ws;
    float* prm = ws + WS_PRM;
    float4* P  = (float4*)(ws + WS_P);

    hipLaunchKernelGGL(k_main, dim3(256), dim3(256), 0, stream,
                       x, xc, W_fc, b_fc, W_g, b_g, W_kin, b_kin,
                       W_kout, b_kout, prm, P);

    hipLaunchKernelGGL(k_scan, dim3(16), dim3(64), 0, stream,
                       P, prm, q);
}